// Round 13
// baseline (505.929 us; speedup 1.0000x reference)
//
#include <hip/hip_runtime.h>
#include <hip/hip_bf16.h>

// CognitiveWorkspace — DIAGNOSTIC: qpart x8 and gfin x8 amplified so both
// exceed the 265µs harness-fill cutoff and report their own counters.
// Partials now live in d_ws (not gate_out) so gfin reps are idempotent.
//   K_copy : flat float4 copy S -> outS (single, ~135 µs measured)
//   K_qpart: query partials -> d_ws          [x8 reps]
//   K_gfin : tag-mean + partial-sum -> gate; hub epilogue  [x8 reps]
//   K_fixup: spoke/hub_priv/tag overwrite (single, ~8 µs)

#define DM 2048      // d_model
#define DSZ 6656     // D_S
#define HUBOFF 4608  // hub_shared offset (floats)
#define TAGOFF 5120
#define NTOK 16384   // B*T
#define DHS 512      // d_hub_shared
#define QREP 8
#define GREP 8

typedef __attribute__((ext_vector_type(8))) short bf16x8;
typedef __attribute__((ext_vector_type(4))) float f32x4;

__device__ __forceinline__ float sigmoidf_(float x) {
  return 1.0f / (1.0f + __expf(-x));
}
__device__ __forceinline__ short f2bf(float x) {
  return (short)__bfloat16_as_ushort(__float2bfloat16(x));
}
__device__ __forceinline__ bf16x8 cvt8(float4 a, float4 b) {
  bf16x8 r;
  r[0] = f2bf(a.x); r[1] = f2bf(a.y); r[2] = f2bf(a.z); r[3] = f2bf(a.w);
  r[4] = f2bf(b.x); r[5] = f2bf(b.y); r[6] = f2bf(b.z); r[7] = f2bf(b.w);
  return r;
}
#define MFMA(a, b, c) __builtin_amdgcn_mfma_f32_16x16x32_bf16((a), (b), (c), 0, 0, 0)

// ---------------------------------------------------------------------------
__global__ __launch_bounds__(256) void cw_copy_kernel(
    const float4* __restrict__ S4, float4* __restrict__ O4)
{
  size_t i = (size_t)blockIdx.x * 256 + threadIdx.x;
  const size_t stride = (size_t)4096 * 256;
#pragma unroll 2
  for (int k = 0; k < 26; ++k) {
    O4[i] = S4[i];
    i += stride;
  }
}

// ---------------------------------------------------------------------------
// K_qpart x8: 8192 blocks: tt = bid>>3, kc = bid&7. Identical math to R12;
// partials -> qp (d_ws) at [tok*512 + kc*64 + q].
// ---------------------------------------------------------------------------
__global__ __launch_bounds__(256) void cw_qpart_kernel(
    const float* __restrict__ H, const float* __restrict__ Wq,
    float* __restrict__ qp)
{
  __shared__ f32x4 part[4][4][64];
  const int tid = threadIdx.x;
  const int w = tid >> 6, l = tid & 63, l15 = l & 15, l4 = l >> 4;
  const int tt = blockIdx.x >> 3, kc = blockIdx.x & 7;
  const int tok0 = tt * 16;
  const int kb = kc * 256 + w * 64 + l4 * 8;
  const float* ha = H + (size_t)(tok0 + l15) * DM + kb;
  const float* wq = Wq + (size_t)l15 * DM + kb;

  for (int rep = 0; rep < QREP; ++rep) {
    __syncthreads();
    float4 ra[2][2], rb[4][2][2];
#pragma unroll
    for (int s = 0; s < 2; ++s) {
      ra[s][0] = *reinterpret_cast<const float4*>(ha + s * 32);
      ra[s][1] = *reinterpret_cast<const float4*>(ha + s * 32 + 4);
    }
#pragma unroll
    for (int q = 0; q < 4; ++q)
#pragma unroll
      for (int s = 0; s < 2; ++s) {
        const float* p = wq + (size_t)q * 16 * DM + s * 32;
        rb[q][s][0] = *reinterpret_cast<const float4*>(p);
        rb[q][s][1] = *reinterpret_cast<const float4*>(p + 4);
      }
    bf16x8 af0 = cvt8(ra[0][0], ra[0][1]);
    bf16x8 af1 = cvt8(ra[1][0], ra[1][1]);
    f32x4 acc[4] = {{0,0,0,0},{0,0,0,0},{0,0,0,0},{0,0,0,0}};
#pragma unroll
    for (int q = 0; q < 4; ++q) {
      acc[q] = MFMA(af0, cvt8(rb[q][0][0], rb[q][0][1]), acc[q]);
      acc[q] = MFMA(af1, cvt8(rb[q][1][0], rb[q][1][1]), acc[q]);
    }
#pragma unroll
    for (int q = 0; q < 4; ++q) part[w][q][l] = acc[q];
    __syncthreads();
    {
      const int qt = tid >> 6, ln = tid & 63;
      f32x4 s0 = part[0][qt][ln], s1 = part[1][qt][ln];
      f32x4 s2 = part[2][qt][ln], s3 = part[3][qt][ln];
      const int row = (ln >> 4) * 4, q = qt * 16 + (ln & 15);
#pragma unroll
      for (int i = 0; i < 4; ++i)
        qp[(size_t)(tok0 + row + i) * DHS + kc * 64 + q] =
            s0[i] + s1[i] + s2[i] + s3[i];
    }
    asm volatile("" ::: "memory");
  }
}

// ---------------------------------------------------------------------------
// K_gfin x8: 1024 blocks x 16 tokens. Reads qp (d_ws); writes gate_out + hub.
// Idempotent across reps.
// ---------------------------------------------------------------------------
__global__ __launch_bounds__(256) void cw_gfin_kernel(
    const float* __restrict__ S, const float* __restrict__ Wg,
    const float* __restrict__ bg, const float* __restrict__ whs,
    const int* __restrict__ lip, const float* __restrict__ qp,
    float* __restrict__ outS, float* __restrict__ gate_out)
{
  __shared__ float gin[16][132];
  __shared__ float gtile[16][516];

  const int tid = threadIdx.x;
  const int li = *lip;
  const int start = (li > 8) ? (li - 8) : 0;
  const int ntags = li - start;
  const float tscale = (ntags > 0) ? (1.0f / (float)ntags) : 0.0f;
  const int trs = TAGOFF + start * 64;
  const int tok0 = blockIdx.x * 16;
  const int w = tid >> 6, l = tid & 63, l15 = l & 15, l4 = l >> 4;

  for (int rep = 0; rep < GREP; ++rep) {
    __syncthreads();
    // ---- tag mean
    {
      const int tk = tid >> 4, t16 = tid & 15;
      const float4* sp =
          reinterpret_cast<const float4*>(S + (size_t)(tok0 + tk) * DSZ + trs) + t16;
      float4 acc = {0.f, 0.f, 0.f, 0.f};
      for (int g = 0; g < ntags; ++g) {
        float4 v = sp[g * 16];
        acc.x += v.x; acc.y += v.y; acc.z += v.z; acc.w += v.w;
      }
      const int d = 64 + t16 * 4;
      gin[tk][d + 0] = acc.x * tscale;
      gin[tk][d + 1] = acc.y * tscale;
      gin[tk][d + 2] = acc.z * tscale;
      gin[tk][d + 3] = acc.w * tscale;
    }
    // ---- sum 8 partials
    {
      const int row = tid >> 4, q4 = tid & 15;
      const float* pp = qp + (size_t)(tok0 + row) * DHS + q4 * 4;
      float4 a = {0.f, 0.f, 0.f, 0.f};
#pragma unroll
      for (int kc = 0; kc < 8; ++kc) {
        float4 v = *reinterpret_cast<const float4*>(pp + kc * 64);
        a.x += v.x; a.y += v.y; a.z += v.z; a.w += v.w;
      }
      gin[row][q4 * 4 + 0] = a.x;
      gin[row][q4 * 4 + 1] = a.y;
      gin[row][q4 * 4 + 2] = a.z;
      gin[row][q4 * 4 + 3] = a.w;
    }
    __syncthreads();

    // ---- Wg MFMA
    bf16x8 afr[4];
#pragma unroll
    for (int ks = 0; ks < 4; ++ks) {
      const float* p = &gin[l15][ks * 32 + l4 * 8];
      afr[ks] = cvt8(*reinterpret_cast<const float4*>(p),
                     *reinterpret_cast<const float4*>(p + 4));
    }
    const float* wgb = Wg + (size_t)l15 * 128 + l4 * 8;
    for (int jp = 0; jp < 4; ++jp) {
      const int ht0 = w * 8 + jp * 2;
      const float* wp0 = wgb + (size_t)ht0 * 16 * 128;
      const float* wp1 = wp0 + 16 * 128;
      float4 r0[4][2], r1[4][2];
#pragma unroll
      for (int ks = 0; ks < 4; ++ks) {
        r0[ks][0] = *reinterpret_cast<const float4*>(wp0 + ks * 32);
        r0[ks][1] = *reinterpret_cast<const float4*>(wp0 + ks * 32 + 4);
        r1[ks][0] = *reinterpret_cast<const float4*>(wp1 + ks * 32);
        r1[ks][1] = *reinterpret_cast<const float4*>(wp1 + ks * 32 + 4);
      }
      f32x4 accA = {0,0,0,0}, accB = {0,0,0,0};
#pragma unroll
      for (int ks = 0; ks < 4; ++ks) {
        accA = MFMA(afr[ks], cvt8(r0[ks][0], r0[ks][1]), accA);
        accB = MFMA(afr[ks], cvt8(r1[ks][0], r1[ks][1]), accB);
      }
#pragma unroll
      for (int t = 0; t < 2; ++t) {
        const f32x4 a = t ? accB : accA;
        const int h = (ht0 + t) * 16 + l15;
        const float bgv = bg[h];
#pragma unroll
        for (int i = 0; i < 4; ++i)
          gtile[l4 * 4 + i][h] = sigmoidf_(a[i] + bgv);
      }
    }
    __syncthreads();

    // ---- coalesced epilogue
#pragma unroll
    for (int r2 = 0; r2 < 8; ++r2) {
      const int idx = r2 * 256 + tid;
      const int row = idx >> 7, qq = idx & 127;
      const int tok = tok0 + row;
      float4 g = *reinterpret_cast<const float4*>(&gtile[row][qq * 4]);
      float4 s = *reinterpret_cast<const float4*>(S + (size_t)tok * DSZ + HUBOFF + qq * 4);
      float4 wv = *reinterpret_cast<const float4*>(whs + (size_t)tok * DHS + qq * 4);
      float4 o;
      o.x = s.x * g.x + wv.x;
      o.y = s.y * g.y + wv.y;
      o.z = s.z * g.z + wv.z;
      o.w = s.w * g.w + wv.w;
      *reinterpret_cast<float4*>(outS + (size_t)tok * DSZ + HUBOFF + qq * 4) = o;
      *reinterpret_cast<float4*>(gate_out + (size_t)tok * DHS + qq * 4) = g;
    }
    asm volatile("" ::: "memory");
  }
}

// ---------------------------------------------------------------------------
__global__ __launch_bounds__(256) void cw_fixup_kernel(
    const float* __restrict__ S,
    const float* __restrict__ w_spoke, const float* __restrict__ w_hub_priv,
    const float* __restrict__ tg, const int* __restrict__ lip,
    float* __restrict__ outS)
{
  const int li = *lip;
  const unsigned sp0 = (unsigned)(li * 32);
  const unsigned hp0 = 768u + (unsigned)(li * 16);
  const unsigned tg0 = 1280u + (unsigned)(li * 16);

  const float4* S4 = reinterpret_cast<const float4*>(S);
  const float4* SP4 = reinterpret_cast<const float4*>(w_spoke);
  const float4* HP4 = reinterpret_cast<const float4*>(w_hub_priv);
  const float4* TG4 = reinterpret_cast<const float4*>(tg);
  float4* O4 = reinterpret_cast<float4*>(outS);

  unsigned t = blockIdx.x * 256u + threadIdx.x;
  unsigned tok = t >> 4;
  unsigned j0 = (t & 15u) * 4u;
  unsigned col;
  const float4* src;
  if (j0 < 32u)      { col = sp0 + j0;         src = SP4 + (size_t)tok * 32u + j0; }
  else if (j0 < 48u) { col = hp0 + (j0 - 32u); src = HP4 + (size_t)tok * 16u + (j0 - 32u); }
  else               { col = tg0 + (j0 - 48u); src = TG4 + (size_t)tok * 16u + (j0 - 48u); }

  size_t idx = (size_t)tok * 1664u + col;
#pragma unroll
  for (int k = 0; k < 4; ++k) {
    float4 s = S4[idx + k];
    float4 v = src[k];
    s.x += v.x; s.y += v.y; s.z += v.z; s.w += v.w;
    O4[idx + k] = s;
  }
}

extern "C" void kernel_launch(void* const* d_in, const int* in_sizes, int n_in,
                              void* d_out, int out_size, void* d_ws, size_t ws_size,
                              hipStream_t stream) {
  (void)in_sizes; (void)n_in; (void)out_size; (void)ws_size;
  const float* S            = (const float*)d_in[0];
  const float* H            = (const float*)d_in[1];
  const float* w_spoke      = (const float*)d_in[2];
  const float* w_hub_priv   = (const float*)d_in[3];
  const float* w_hub_shared = (const float*)d_in[4];
  const float* tg           = (const float*)d_in[5];
  const float* Wq           = (const float*)d_in[6];
  const float* Wg           = (const float*)d_in[7];
  const float* bg           = (const float*)d_in[8];
  const int*   lip          = (const int*)d_in[9];

  float* outS = (float*)d_out;
  float* gate_out = outS + (size_t)NTOK * DSZ;
  float* qws = (float*)d_ws;   // partials: NTOK*512 floats = 33.5 MB

  cw_copy_kernel<<<4096, 256, 0, stream>>>(
      reinterpret_cast<const float4*>(S), reinterpret_cast<float4*>(outS));
  cw_qpart_kernel<<<8192, 256, 0, stream>>>(H, Wq, qws);
  cw_gfin_kernel<<<1024, 256, 0, stream>>>(S, Wg, bg, w_hub_shared, lip, qws,
                                           outS, gate_out);
  cw_fixup_kernel<<<1024, 256, 0, stream>>>(S, w_spoke, w_hub_priv, tg, lip, outS);
}

// Round 14
// 324.373 us; speedup vs baseline: 1.5597x; 1.5597x over previous
//
#include <hip/hip_runtime.h>
#include <hip/hip_bf16.h>

// CognitiveWorkspace — 3 dispatches.
//   K_copy : flat float4 copy S -> outS (135 µs measured, R10)
//   K_gate : full gate pipeline; H staged via LDS with copy-pattern
//            (1KB-contiguous per wave-instruction) global reads -> bf16 LDS;
//            MFMA frags from ds_read_b128. Writes gate_out + hub region.
//   K_fixup: spoke/hub_priv/tag overwrite (~8 µs)

#define DM 2048      // d_model
#define DSZ 6656     // D_S
#define HUBOFF 4608  // hub_shared offset (floats)
#define TAGOFF 5120
#define NTOK 16384   // B*T
#define DHS 512      // d_hub_shared
#define HSTRIDE 1048 // LDS row stride in bf16 (1024 + 24 pad; 2096B ≡ 12 dw mod 32)

typedef __attribute__((ext_vector_type(8))) short bf16x8;
typedef __attribute__((ext_vector_type(4))) short s16x4;
typedef __attribute__((ext_vector_type(4))) float f32x4;

__device__ __forceinline__ float sigmoidf_(float x) {
  return 1.0f / (1.0f + __expf(-x));
}
__device__ __forceinline__ short f2bf(float x) {
  return (short)__bfloat16_as_ushort(__float2bfloat16(x));
}
__device__ __forceinline__ bf16x8 cvt8(float4 a, float4 b) {
  bf16x8 r;
  r[0] = f2bf(a.x); r[1] = f2bf(a.y); r[2] = f2bf(a.z); r[3] = f2bf(a.w);
  r[4] = f2bf(b.x); r[5] = f2bf(b.y); r[6] = f2bf(b.z); r[7] = f2bf(b.w);
  return r;
}
#define MFMA(a, b, c) __builtin_amdgcn_mfma_f32_16x16x32_bf16((a), (b), (c), 0, 0, 0)

// ---------------------------------------------------------------------------
__global__ __launch_bounds__(256) void cw_copy_kernel(
    const float4* __restrict__ S4, float4* __restrict__ O4)
{
  size_t i = (size_t)blockIdx.x * 256 + threadIdx.x;
  const size_t stride = (size_t)4096 * 256;
#pragma unroll 2
  for (int k = 0; k < 26; ++k) {
    O4[i] = S4[i];
    i += stride;
  }
}

// ---------------------------------------------------------------------------
// K_gate: 1024 blocks x 16 tokens x 256 thr (4 waves).
//  tag-mean -> gin[tok][64..127]
//  query: 2 K-chunks of 1024: stage H[16][1024] -> bf16 LDS (contiguous 1KB
//    global reads per wave-instr), MFMA A from LDS, B (Wq) from global/L2.
//    wave w owns q-tile w. -> gin[tok][0..63]
//  Wg MFMA -> gtile; coalesced epilogue: gate_out + outS hub.
// MFMA 16x16x32 bf16 (m89): A row = lane&15, k=(lane>>4)*8+e;
// C/D: col = lane&15, row = (lane>>4)*4+reg.
// ---------------------------------------------------------------------------
__global__ __launch_bounds__(256) void cw_gate_kernel(
    const float* __restrict__ S, const float* __restrict__ H,
    const float* __restrict__ Wq, const float* __restrict__ Wg,
    const float* __restrict__ bg, const float* __restrict__ whs,
    const int* __restrict__ lip,
    float* __restrict__ outS, float* __restrict__ gate_out)
{
  __shared__ float gin[16][132];                       // 8.4 KB
  __shared__ __align__(16) char smem[16 * HSTRIDE * 2]; // 33.5 KB, unioned:
  short (*hds)[HSTRIDE] = (short (*)[HSTRIDE])smem;     //  H-stage (bf16)
  float (*gtile)[516]   = (float (*)[516])smem;         //  gate tile (fp32)

  const int tid = threadIdx.x;
  const int li = *lip;
  const int start = (li > 8) ? (li - 8) : 0;
  const int ntags = li - start;
  const float tscale = (ntags > 0) ? (1.0f / (float)ntags) : 0.0f;
  const int trs = TAGOFF + start * 64;
  const int tok0 = blockIdx.x * 16;
  const int w = tid >> 6, l = tid & 63, l15 = l & 15, l4 = l >> 4;

  // ---- tag mean -> gin[tok][64..127]
  {
    const int tk = tid >> 4, t16 = tid & 15;
    const float4* sp =
        reinterpret_cast<const float4*>(S + (size_t)(tok0 + tk) * DSZ + trs) + t16;
    float4 acc = {0.f, 0.f, 0.f, 0.f};
    for (int g = 0; g < ntags; ++g) {
      float4 v = sp[g * 16];
      acc.x += v.x; acc.y += v.y; acc.z += v.z; acc.w += v.w;
    }
    const int d = 64 + t16 * 4;
    gin[tk][d + 0] = acc.x * tscale;
    gin[tk][d + 1] = acc.y * tscale;
    gin[tk][d + 2] = acc.z * tscale;
    gin[tk][d + 3] = acc.w * tscale;
  }

  // ---- query = H * Wq^T over 2 K-chunks; wave w = q-tile w
  const int q0 = w * 16;
  f32x4 qacc = {0.f, 0.f, 0.f, 0.f};
  for (int kc = 0; kc < 2; ++kc) {
    // stage: wave w loads rows 4w..4w+3, 4KB each, fully contiguous 1KB/instr
    float4 st[16];
    const float* hb = H + (size_t)(tok0 + w * 4) * DM + kc * 1024;
#pragma unroll
    for (int j = 0; j < 16; ++j)
      st[j] = *reinterpret_cast<const float4*>(
          hb + (size_t)(j >> 2) * DM + (j & 3) * 256 + l * 4);
    __syncthreads();                 // prev chunk's LDS reads complete
#pragma unroll
    for (int j = 0; j < 16; ++j) {
      s16x4 v;
      v[0] = f2bf(st[j].x); v[1] = f2bf(st[j].y);
      v[2] = f2bf(st[j].z); v[3] = f2bf(st[j].w);
      *reinterpret_cast<s16x4*>(&hds[w * 4 + (j >> 2)][(j & 3) * 256 + l * 4]) = v;
    }
    __syncthreads();
    const float* wqb = Wq + (size_t)(q0 + l15) * DM + kc * 1024 + l4 * 8;
#pragma unroll 4
    for (int ks = 0; ks < 32; ++ks) {
      bf16x8 af = *reinterpret_cast<const bf16x8*>(&hds[l15][ks * 32 + l4 * 8]);
      float4 b0 = *reinterpret_cast<const float4*>(wqb + ks * 32);
      float4 b1 = *reinterpret_cast<const float4*>(wqb + ks * 32 + 4);
      qacc = MFMA(af, cvt8(b0, b1), qacc);
    }
  }
  // query -> gin[tok][0..63]
#pragma unroll
  for (int i = 0; i < 4; ++i)
    gin[l4 * 4 + i][q0 + l15] = qacc[i];
  __syncthreads();   // gin complete AND all hds reads done (gtile may reuse smem)

  // ---- Wg MFMA -> gtile
  bf16x8 afr[4];
#pragma unroll
  for (int ks = 0; ks < 4; ++ks) {
    const float* p = &gin[l15][ks * 32 + l4 * 8];
    afr[ks] = cvt8(*reinterpret_cast<const float4*>(p),
                   *reinterpret_cast<const float4*>(p + 4));
  }
  const float* wgb = Wg + (size_t)l15 * 128 + l4 * 8;
  for (int jp = 0; jp < 4; ++jp) {
    const int ht0 = w * 8 + jp * 2;
    const float* wp0 = wgb + (size_t)ht0 * 16 * 128;
    const float* wp1 = wp0 + 16 * 128;
    float4 r0[4][2], r1[4][2];
#pragma unroll
    for (int ks = 0; ks < 4; ++ks) {
      r0[ks][0] = *reinterpret_cast<const float4*>(wp0 + ks * 32);
      r0[ks][1] = *reinterpret_cast<const float4*>(wp0 + ks * 32 + 4);
      r1[ks][0] = *reinterpret_cast<const float4*>(wp1 + ks * 32);
      r1[ks][1] = *reinterpret_cast<const float4*>(wp1 + ks * 32 + 4);
    }
    f32x4 accA = {0.f,0.f,0.f,0.f}, accB = {0.f,0.f,0.f,0.f};
#pragma unroll
    for (int ks = 0; ks < 4; ++ks) {
      accA = MFMA(afr[ks], cvt8(r0[ks][0], r0[ks][1]), accA);
      accB = MFMA(afr[ks], cvt8(r1[ks][0], r1[ks][1]), accB);
    }
#pragma unroll
    for (int t = 0; t < 2; ++t) {
      const f32x4 a = t ? accB : accA;
      const int h = (ht0 + t) * 16 + l15;
      const float bgv = bg[h];
#pragma unroll
      for (int i = 0; i < 4; ++i)
        gtile[l4 * 4 + i][h] = sigmoidf_(a[i] + bgv);
    }
  }
  __syncthreads();

  // ---- coalesced epilogue: gate_out + outS hub (= S*g + whs)
#pragma unroll
  for (int r2 = 0; r2 < 8; ++r2) {
    const int idx = r2 * 256 + tid;
    const int row = idx >> 7, qq = idx & 127;
    const int tok = tok0 + row;
    float4 g = *reinterpret_cast<const float4*>(&gtile[row][qq * 4]);
    float4 s = *reinterpret_cast<const float4*>(S + (size_t)tok * DSZ + HUBOFF + qq * 4);
    float4 wv = *reinterpret_cast<const float4*>(whs + (size_t)tok * DHS + qq * 4);
    float4 o;
    o.x = s.x * g.x + wv.x;
    o.y = s.y * g.y + wv.y;
    o.z = s.z * g.z + wv.z;
    o.w = s.w * g.w + wv.w;
    *reinterpret_cast<float4*>(outS + (size_t)tok * DSZ + HUBOFF + qq * 4) = o;
    *reinterpret_cast<float4*>(gate_out + (size_t)tok * DHS + qq * 4) = g;
  }
}

// ---------------------------------------------------------------------------
__global__ __launch_bounds__(256) void cw_fixup_kernel(
    const float* __restrict__ S,
    const float* __restrict__ w_spoke, const float* __restrict__ w_hub_priv,
    const float* __restrict__ tg, const int* __restrict__ lip,
    float* __restrict__ outS)
{
  const int li = *lip;
  const unsigned sp0 = (unsigned)(li * 32);
  const unsigned hp0 = 768u + (unsigned)(li * 16);
  const unsigned tg0 = 1280u + (unsigned)(li * 16);

  const float4* S4 = reinterpret_cast<const float4*>(S);
  const float4* SP4 = reinterpret_cast<const float4*>(w_spoke);
  const float4* HP4 = reinterpret_cast<const float4*>(w_hub_priv);
  const float4* TG4 = reinterpret_cast<const float4*>(tg);
  float4* O4 = reinterpret_cast<float4*>(outS);

  unsigned t = blockIdx.x * 256u + threadIdx.x;   // 0..262143
  unsigned tok = t >> 4;
  unsigned j0 = (t & 15u) * 4u;
  unsigned col;
  const float4* src;
  if (j0 < 32u)      { col = sp0 + j0;         src = SP4 + (size_t)tok * 32u + j0; }
  else if (j0 < 48u) { col = hp0 + (j0 - 32u); src = HP4 + (size_t)tok * 16u + (j0 - 32u); }
  else               { col = tg0 + (j0 - 48u); src = TG4 + (size_t)tok * 16u + (j0 - 48u); }

  size_t idx = (size_t)tok * 1664u + col;
#pragma unroll
  for (int k = 0; k < 4; ++k) {
    float4 s = S4[idx + k];
    float4 v = src[k];
    s.x += v.x; s.y += v.y; s.z += v.z; s.w += v.w;
    O4[idx + k] = s;
  }
}

extern "C" void kernel_launch(void* const* d_in, const int* in_sizes, int n_in,
                              void* d_out, int out_size, void* d_ws, size_t ws_size,
                              hipStream_t stream) {
  (void)in_sizes; (void)n_in; (void)out_size; (void)d_ws; (void)ws_size;
  const float* S            = (const float*)d_in[0];
  const float* H            = (const float*)d_in[1];
  const float* w_spoke      = (const float*)d_in[2];
  const float* w_hub_priv   = (const float*)d_in[3];
  const float* w_hub_shared = (const float*)d_in[4];
  const float* tg           = (const float*)d_in[5];
  const float* Wq           = (const float*)d_in[6];
  const float* Wg           = (const float*)d_in[7];
  const float* bg           = (const float*)d_in[8];
  const int*   lip          = (const int*)d_in[9];

  float* outS = (float*)d_out;
  float* gate_out = outS + (size_t)NTOK * DSZ;

  cw_copy_kernel<<<4096, 256, 0, stream>>>(
      reinterpret_cast<const float4*>(S), reinterpret_cast<float4*>(outS));
  cw_gate_kernel<<<1024, 256, 0, stream>>>(S, H, Wq, Wg, bg, w_hub_shared,
                                           lip, outS, gate_out);
  cw_fixup_kernel<<<1024, 256, 0, stream>>>(S, w_spoke, w_hub_priv, tg, lip, outS);
}

// Round 15
// 284.911 us; speedup vs baseline: 1.7757x; 1.1385x over previous
//
#include <hip/hip_runtime.h>
#include <hip/hip_bf16.h>

// CognitiveWorkspace — ONE fused kernel, 1024 blocks x 16 tokens x 256 thr.
//  ph0: stream 16 full rows S->out (contiguous), apply spoke/priv/tag adds,
//       capture hub quads + tag-window quads into LDS (bf16). Hub not written.
//  ph1: tag-mean from LDS -> gin[tok][64..127]
//  ph2: query = H*Wq^T (H staged via LDS, contiguous 1KB reads) -> gin[0..63]
//  ph3: Wg MFMA -> gtile; epilogue: out_hub = hub_lds*g + whs, gate_out = g
// S touched once (stream); out written once per element; no d_out reads.

#define DM 2048      // d_model
#define DSZ 6656     // D_S
#define HUBOFF 4608  // hub_shared offset (floats)
#define TAGOFF 5120
#define NTOK 16384   // B*T
#define DHS 512      // d_hub_shared
#define HSTRIDE 1048 // H-stage LDS row stride (bf16)

typedef __attribute__((ext_vector_type(8))) short bf16x8;
typedef __attribute__((ext_vector_type(4))) short s16x4;
typedef __attribute__((ext_vector_type(4))) float f32x4;

__device__ __forceinline__ float sigmoidf_(float x) {
  return 1.0f / (1.0f + __expf(-x));
}
__device__ __forceinline__ short f2bf(float x) {
  return (short)__bfloat16_as_ushort(__float2bfloat16(x));
}
__device__ __forceinline__ float bf2f(short x) {
  return __builtin_bit_cast(float, (unsigned)((unsigned short)x) << 16);
}
__device__ __forceinline__ bf16x8 cvt8(float4 a, float4 b) {
  bf16x8 r;
  r[0] = f2bf(a.x); r[1] = f2bf(a.y); r[2] = f2bf(a.z); r[3] = f2bf(a.w);
  r[4] = f2bf(b.x); r[5] = f2bf(b.y); r[6] = f2bf(b.z); r[7] = f2bf(b.w);
  return r;
}
#define MFMA(a, b, c) __builtin_amdgcn_mfma_f32_16x16x32_bf16((a), (b), (c), 0, 0, 0)

__global__ __launch_bounds__(256) void cw_fused_kernel(
    const float* __restrict__ S, const float* __restrict__ H,
    const float* __restrict__ Wq, const float* __restrict__ Wg,
    const float* __restrict__ bg, const float* __restrict__ whs,
    const float* __restrict__ w_spoke, const float* __restrict__ w_hub_priv,
    const float* __restrict__ tgin, const int* __restrict__ lip,
    float* __restrict__ outS, float* __restrict__ gate_out)
{
  __shared__ float gin[16][132];                        // 8.4 KB
  __shared__ short tagb[16][520];                       // 16.6 KB (bf16 tag window)
  __shared__ short hubb[16][520];                       // 16.6 KB (bf16 S-hub)
  __shared__ __align__(16) char smem[16 * HSTRIDE * 2]; // 33.5 KB union:
  short (*hds)[HSTRIDE] = (short (*)[HSTRIDE])smem;     //   H-stage (bf16)
  float (*gtile)[516]   = (float (*)[516])smem;         //   gate tile (fp32)

  const int tid = threadIdx.x;
  const int li = *lip;
  const int start = (li > 8) ? (li - 8) : 0;
  const int ntags = li - start;
  const float tscale = (ntags > 0) ? (1.0f / (float)ntags) : 0.0f;
  const int tok0 = blockIdx.x * 16;
  const int w = tid >> 6, l = tid & 63, l15 = l & 15, l4 = l >> 4;

  // region bounds in quads
  const int sp0 = li * 32;                 // spoke add [sp0, sp0+32)
  const int hp0 = 768 + li * 16;           // hub_priv add [hp0, hp0+16)
  const int tg0 = 1280 + li * 16;          // tag add [tg0, tg0+16)
  const int tq0 = 1280 + start * 16;       // tag capture [tq0, tq0+16*ntags)
  const int tq1 = tq0 + 16 * ntags;

  const float4* S4 = reinterpret_cast<const float4*>(S);
  const float4* SP4 = reinterpret_cast<const float4*>(w_spoke);
  const float4* HP4 = reinterpret_cast<const float4*>(w_hub_priv);
  const float4* TG4 = reinterpret_cast<const float4*>(tgin);
  float4* O4 = reinterpret_cast<float4*>(outS);

  // ---- ph0: stream 16 rows; 4-row batches for MLP
  for (int j = 0; j < 7; ++j) {
    const int c = j * 256 + tid;
    if (c < 1664) {
      const bool inhub = (c >= 1152 && c < 1280);
#pragma unroll
      for (int rq = 0; rq < 4; ++rq) {
        float4 sv[4];
#pragma unroll
        for (int k = 0; k < 4; ++k)
          sv[k] = S4[(size_t)(tok0 + rq * 4 + k) * 1664u + c];
#pragma unroll
        for (int k = 0; k < 4; ++k) {
          const int r = rq * 4 + k;
          float4 s = sv[k];
          if (inhub) {
            s16x4 v;
            v[0] = f2bf(s.x); v[1] = f2bf(s.y);
            v[2] = f2bf(s.z); v[3] = f2bf(s.w);
            *reinterpret_cast<s16x4*>(&hubb[r][(c - 1152) * 4]) = v;
          } else {
            if (c >= tq0 && c < tq1) {
              s16x4 v;
              v[0] = f2bf(s.x); v[1] = f2bf(s.y);
              v[2] = f2bf(s.z); v[3] = f2bf(s.w);
              *reinterpret_cast<s16x4*>(&tagb[r][(c - tq0) * 4]) = v;
            }
            float4 o = s;
            if (c >= sp0 && c < sp0 + 32) {
              float4 v = SP4[(size_t)(tok0 + r) * 32u + (c - sp0)];
              o.x += v.x; o.y += v.y; o.z += v.z; o.w += v.w;
            } else if (c >= hp0 && c < hp0 + 16) {
              float4 v = HP4[(size_t)(tok0 + r) * 16u + (c - hp0)];
              o.x += v.x; o.y += v.y; o.z += v.z; o.w += v.w;
            } else if (c >= tg0 && c < tg0 + 16) {
              float4 v = TG4[(size_t)(tok0 + r) * 16u + (c - tg0)];
              o.x += v.x; o.y += v.y; o.z += v.z; o.w += v.w;
            }
            O4[(size_t)(tok0 + r) * 1664u + c] = o;
          }
        }
      }
    }
  }
  __syncthreads();

  // ---- ph1: tag-mean from LDS -> gin[tok][64..127]
  {
    const int tk = tid >> 4, t16 = tid & 15;
    float a0 = 0.f, a1 = 0.f, a2 = 0.f, a3 = 0.f;
    for (int g = 0; g < ntags; ++g) {
      s16x4 v = *reinterpret_cast<const s16x4*>(&tagb[tk][g * 64 + t16 * 4]);
      a0 += bf2f(v[0]); a1 += bf2f(v[1]); a2 += bf2f(v[2]); a3 += bf2f(v[3]);
    }
    const int d = 64 + t16 * 4;
    gin[tk][d + 0] = a0 * tscale;
    gin[tk][d + 1] = a1 * tscale;
    gin[tk][d + 2] = a2 * tscale;
    gin[tk][d + 3] = a3 * tscale;
  }

  // ---- ph2: query = H * Wq^T (2 K-chunks of 1024; H staged contiguous)
  const int q0 = w * 16;
  f32x4 qacc = {0.f, 0.f, 0.f, 0.f};
  for (int kc = 0; kc < 2; ++kc) {
    float4 st[16];
    const float* hb = H + (size_t)(tok0 + w * 4) * DM + kc * 1024;
#pragma unroll
    for (int j = 0; j < 16; ++j)
      st[j] = *reinterpret_cast<const float4*>(
          hb + (size_t)(j >> 2) * DM + (j & 3) * 256 + l * 4);
    __syncthreads();
#pragma unroll
    for (int j = 0; j < 16; ++j) {
      s16x4 v;
      v[0] = f2bf(st[j].x); v[1] = f2bf(st[j].y);
      v[2] = f2bf(st[j].z); v[3] = f2bf(st[j].w);
      *reinterpret_cast<s16x4*>(&hds[w * 4 + (j >> 2)][(j & 3) * 256 + l * 4]) = v;
    }
    __syncthreads();
    const float* wqb = Wq + (size_t)(q0 + l15) * DM + kc * 1024 + l4 * 8;
#pragma unroll 4
    for (int ks = 0; ks < 32; ++ks) {
      bf16x8 af = *reinterpret_cast<const bf16x8*>(&hds[l15][ks * 32 + l4 * 8]);
      float4 b0 = *reinterpret_cast<const float4*>(wqb + ks * 32);
      float4 b1 = *reinterpret_cast<const float4*>(wqb + ks * 32 + 4);
      qacc = MFMA(af, cvt8(b0, b1), qacc);
    }
  }
#pragma unroll
  for (int i = 0; i < 4; ++i)
    gin[l4 * 4 + i][q0 + l15] = qacc[i];
  __syncthreads();   // gin complete; all hds reads done (gtile reuses smem)

  // ---- ph3: Wg MFMA -> gtile
  bf16x8 afr[4];
#pragma unroll
  for (int ks = 0; ks < 4; ++ks) {
    const float* p = &gin[l15][ks * 32 + l4 * 8];
    afr[ks] = cvt8(*reinterpret_cast<const float4*>(p),
                   *reinterpret_cast<const float4*>(p + 4));
  }
  const float* wgb = Wg + (size_t)l15 * 128 + l4 * 8;
  for (int jp = 0; jp < 4; ++jp) {
    const int ht0 = w * 8 + jp * 2;
    const float* wp0 = wgb + (size_t)ht0 * 16 * 128;
    const float* wp1 = wp0 + 16 * 128;
    float4 r0[4][2], r1[4][2];
#pragma unroll
    for (int ks = 0; ks < 4; ++ks) {
      r0[ks][0] = *reinterpret_cast<const float4*>(wp0 + ks * 32);
      r0[ks][1] = *reinterpret_cast<const float4*>(wp0 + ks * 32 + 4);
      r1[ks][0] = *reinterpret_cast<const float4*>(wp1 + ks * 32);
      r1[ks][1] = *reinterpret_cast<const float4*>(wp1 + ks * 32 + 4);
    }
    f32x4 accA = {0.f,0.f,0.f,0.f}, accB = {0.f,0.f,0.f,0.f};
#pragma unroll
    for (int ks = 0; ks < 4; ++ks) {
      accA = MFMA(afr[ks], cvt8(r0[ks][0], r0[ks][1]), accA);
      accB = MFMA(afr[ks], cvt8(r1[ks][0], r1[ks][1]), accB);
    }
#pragma unroll
    for (int t = 0; t < 2; ++t) {
      const f32x4 a = t ? accB : accA;
      const int h = (ht0 + t) * 16 + l15;
      const float bgv = bg[h];
#pragma unroll
      for (int i = 0; i < 4; ++i)
        gtile[l4 * 4 + i][h] = sigmoidf_(a[i] + bgv);
    }
  }
  __syncthreads();

  // ---- epilogue: out_hub = hub_lds * g + whs; gate_out = g (coalesced)
#pragma unroll
  for (int r2 = 0; r2 < 8; ++r2) {
    const int idx = r2 * 256 + tid;
    const int row = idx >> 7, qq = idx & 127;
    const int tok = tok0 + row;
    float4 g = *reinterpret_cast<const float4*>(&gtile[row][qq * 4]);
    s16x4 sh = *reinterpret_cast<const s16x4*>(&hubb[row][qq * 4]);
    float4 wv = *reinterpret_cast<const float4*>(whs + (size_t)tok * DHS + qq * 4);
    float4 o;
    o.x = bf2f(sh[0]) * g.x + wv.x;
    o.y = bf2f(sh[1]) * g.y + wv.y;
    o.z = bf2f(sh[2]) * g.z + wv.z;
    o.w = bf2f(sh[3]) * g.w + wv.w;
    *reinterpret_cast<float4*>(outS + (size_t)tok * DSZ + HUBOFF + qq * 4) = o;
    *reinterpret_cast<float4*>(gate_out + (size_t)tok * DHS + qq * 4) = g;
  }
}

extern "C" void kernel_launch(void* const* d_in, const int* in_sizes, int n_in,
                              void* d_out, int out_size, void* d_ws, size_t ws_size,
                              hipStream_t stream) {
  (void)in_sizes; (void)n_in; (void)out_size; (void)d_ws; (void)ws_size;
  const float* S            = (const float*)d_in[0];
  const float* H            = (const float*)d_in[1];
  const float* w_spoke      = (const float*)d_in[2];
  const float* w_hub_priv   = (const float*)d_in[3];
  const float* w_hub_shared = (const float*)d_in[4];
  const float* tgin         = (const float*)d_in[5];
  const float* Wq           = (const float*)d_in[6];
  const float* Wg           = (const float*)d_in[7];
  const float* bg           = (const float*)d_in[8];
  const int*   lip          = (const int*)d_in[9];

  float* outS = (float*)d_out;
  float* gate_out = outS + (size_t)NTOK * DSZ;

  cw_fused_kernel<<<1024, 256, 0, stream>>>(
      S, H, Wq, Wg, bg, w_hub_shared, w_spoke, w_hub_priv, tgin, lip,
      outS, gate_out);
}